// Round 2
// baseline (419.276 us; speedup 1.0000x reference)
//
#include <hip/hip_runtime.h>
#include <hip/hip_bf16.h>
#include <stdint.h>

#define NN 100000
#define NE 1600000
#define NF 128
#define NTILE2 ((NN + 127) / 128)   // 782 row tiles of 128 (gemm, 8 waves/block)
#define B_BKT 1563                  // 64-node buckets
#define NB2 128                     // binning blocks
#define EPB (NE / NB2)              // 12500 edges per binning block
#define NCNT (B_BKT * NB2)          // 200,064 segment counters
#define SC2A ((NCNT + 255) / 256)   // 782 scan blocks

typedef __attribute__((ext_vector_type(8))) __bf16 bf16x8;
typedef __attribute__((ext_vector_type(4))) float floatx4;
typedef __attribute__((ext_vector_type(4))) unsigned short ushortx4;
typedef __attribute__((ext_vector_type(8))) unsigned short ushortx8;
typedef __attribute__((ext_vector_type(4))) unsigned int uintx4;

static __device__ __forceinline__ unsigned short f2bf(float x) {
    union { float f; unsigned u; } v; v.f = x;
    unsigned r = v.u + 0x7fffu + ((v.u >> 16) & 1u);   // RNE
    return (unsigned short)(r >> 16);
}
static __device__ __forceinline__ float bflo(unsigned w) {
    union { unsigned u; float f; } v; v.u = w << 16; return v.f;
}
static __device__ __forceinline__ float bfhi(unsigned w) {
    union { unsigned u; float f; } v; v.u = w & 0xffff0000u; return v.f;
}

// fp32 -> bf16
__global__ void k_convert(const float* __restrict__ s, unsigned short* __restrict__ d, int n4) {
    int i = blockIdx.x * blockDim.x + threadIdx.x;
    if (i < n4) {
        floatx4 f = __builtin_nontemporal_load((const floatx4*)s + i);
        ushortx4 o;
        o.x = f2bf(f.x); o.y = f2bf(f.y); o.z = f2bf(f.z); o.w = f2bf(f.w);
        __builtin_nontemporal_store(o, (ushortx4*)d + i);
    }
}

// Build W2t: [n][k] bf16, k in 0..255 = [Wv ; Wu], 16B k-chunks XOR-swizzled
__global__ void k_prep(const float* __restrict__ wv, const float* __restrict__ wu,
                       unsigned short* __restrict__ w2t) {
    int id = blockIdx.x * 256 + threadIdx.x;   // 0..4095
    if (id >= 128 * 32) return;
    int n = id >> 5, kg = id & 31;
    const float* srcm = (kg < 16) ? wv : wu;
    int k0 = (kg & 15) * 8;
    ushortx8 o;
#pragma unroll
    for (int j = 0; j < 8; ++j)
        o[j] = f2bf(srcm[(k0 + j) * 128 + n]);
    int dchunk = n * 32 + (kg ^ (n & 7));
    *(ushortx8*)(w2t + dchunk * 8) = o;
}

// pass 1: per-block histogram over 1563 fine buckets (LDS atomics only)
__global__ void k_count(const int* __restrict__ dst, int* __restrict__ counts) {
    __shared__ int h[B_BKT];
    int tid = threadIdx.x;
    for (int i = tid; i < B_BKT; i += 256) h[i] = 0;
    __syncthreads();
    int base = blockIdx.x * EPB, end = base + EPB;
    for (int i = base + tid; i < end; i += 256) {
        int d = __builtin_nontemporal_load(&dst[i]);
        atomicAdd(&h[d >> 6], 1);
    }
    __syncthreads();
    for (int i = tid; i < B_BKT; i += 256)
        counts[i * NB2 + blockIdx.x] = h[i];
}

// hierarchical exclusive scan of the 200,064 counts (bucket-major)
__global__ void k_scan2_a(int* __restrict__ counts, int* __restrict__ bsums) {
    __shared__ int sh[256];
    int i = blockIdx.x * 256 + threadIdx.x;
    int v = (i < NCNT) ? counts[i] : 0;
    sh[threadIdx.x] = v;
    __syncthreads();
    for (int off = 1; off < 256; off <<= 1) {
        int u = (threadIdx.x >= off) ? sh[threadIdx.x - off] : 0;
        __syncthreads();
        sh[threadIdx.x] += u;
        __syncthreads();
    }
    if (i < NCNT) counts[i] = sh[threadIdx.x] - v;
    if (threadIdx.x == 255) bsums[blockIdx.x] = sh[255];
}
__global__ void k_scan2_b(int* __restrict__ bsums) {
    __shared__ int sh[1024];
    int t = threadIdx.x;
    int v = (t < SC2A) ? bsums[t] : 0;
    sh[t] = v;
    __syncthreads();
    for (int off = 1; off < 1024; off <<= 1) {
        int u = (t >= off) ? sh[t - off] : 0;
        __syncthreads();
        sh[t] += u;
        __syncthreads();
    }
    if (t < SC2A) bsums[t] = sh[t] - v;
}
__global__ void k_scan2_c(int* __restrict__ counts, const int* __restrict__ bsums) {
    int i = blockIdx.x * 256 + threadIdx.x;
    if (i < NCNT) counts[i] += bsums[blockIdx.x];
}

// pass 2: deterministic scatter into bucket-sorted stream; LDS cursors only
__global__ void k_binscatter(const int* __restrict__ src, const int* __restrict__ dst,
                             const int* __restrict__ counts, unsigned* __restrict__ streams) {
    __shared__ int cur[B_BKT];
    int tid = threadIdx.x;
    for (int i = tid; i < B_BKT; i += 256)
        cur[i] = counts[i * NB2 + blockIdx.x];
    __syncthreads();
    int base = blockIdx.x * EPB, end = base + EPB;
    for (int i = base + tid; i < end; i += 256) {
        int d = __builtin_nontemporal_load(&dst[i]);
        int s = __builtin_nontemporal_load(&src[i]);
        int b = d >> 6;
        unsigned packed = ((unsigned)(d & 63) << 17) | (unsigned)s;
        int pos = atomicAdd(&cur[b], 1);
        streams[pos] = packed;
    }
}

// finalize CSR per bucket: histogram 64 nodes, tiny serial scan, write offs,
// scatter src into the block's OWN contiguous [s,e) csr range
__global__ void k_csr(const unsigned* __restrict__ streams,
                      const int* __restrict__ counts,
                      int* __restrict__ offs, int* __restrict__ csr) {
    __shared__ int hist[64];
    __shared__ int nodeoff[65];
    int tid = threadIdx.x;
    int bkt = blockIdx.x;
    int s = counts[bkt * NB2];
    int e = (bkt == B_BKT - 1) ? NE : counts[(bkt + 1) * NB2];
    if (tid < 64) hist[tid] = 0;
    __syncthreads();
    for (int i = s + tid; i < e; i += 256)
        atomicAdd(&hist[streams[i] >> 17], 1);
    __syncthreads();
    if (tid == 0) {
        int run = 0;
#pragma unroll
        for (int n = 0; n < 64; ++n) { nodeoff[n] = run; run += hist[n]; }
        nodeoff[64] = run;
    }
    __syncthreads();
    if (tid < 64) {
        int node = bkt * 64 + tid;
        if (node < NN) offs[node] = s + nodeoff[tid];
        hist[tid] = nodeoff[tid];          // reuse as relative cursor
    }
    if (bkt == B_BKT - 1 && tid == 0) offs[NN] = NE;
    __syncthreads();
    for (int i = s + tid; i < e; i += 256) {
        unsigned v = streams[i];
        int p = atomicAdd(&hist[v >> 17], 1);
        csr[s + p] = (int)(v & 0x1FFFFu);
    }
}

// one wave per node. 4 lane-groups of 16; each group owns one edge per step,
// each lane loads 16B (8 feats) of the row -> 4 edges per load instruction.
__global__ void k_aggregate(const unsigned short* __restrict__ featb,
                            const int* __restrict__ offs,
                            const int* __restrict__ csr,
                            unsigned short* __restrict__ aggb) {
    int lane = threadIdx.x & 63;
    int node = blockIdx.x * 4 + (threadIdx.x >> 6);
    if (node >= NN) return;
    int g = lane >> 4;        // edge subgroup 0..3
    int l16 = lane & 15;      // feat chunk: 8 feats at l16*8
    int s0 = offs[node], s1 = offs[node + 1];
    float acc[8];
#pragma unroll
    for (int j = 0; j < 8; ++j) acc[j] = 0.f;

    int base = s0 + g;
    // main loop: 8 edges per wave iteration (2 per group), independent loads
    for (; base + 4 < s1; base += 8) {
        int e0 = __builtin_nontemporal_load(&csr[base]);
        int e1 = __builtin_nontemporal_load(&csr[base + 4]);
        uintx4 w0 = *(const uintx4*)(featb + (e0 << 7) + (l16 << 3));
        uintx4 w1 = *(const uintx4*)(featb + (e1 << 7) + (l16 << 3));
        acc[0] += bflo(w0.x); acc[1] += bfhi(w0.x);
        acc[2] += bflo(w0.y); acc[3] += bfhi(w0.y);
        acc[4] += bflo(w0.z); acc[5] += bfhi(w0.z);
        acc[6] += bflo(w0.w); acc[7] += bfhi(w0.w);
        acc[0] += bflo(w1.x); acc[1] += bfhi(w1.x);
        acc[2] += bflo(w1.y); acc[3] += bfhi(w1.y);
        acc[4] += bflo(w1.z); acc[5] += bfhi(w1.z);
        acc[6] += bflo(w1.w); acc[7] += bfhi(w1.w);
    }
    if (base < s1) {           // remainder: at most one edge per group
        int e0 = __builtin_nontemporal_load(&csr[base]);
        uintx4 w0 = *(const uintx4*)(featb + (e0 << 7) + (l16 << 3));
        acc[0] += bflo(w0.x); acc[1] += bfhi(w0.x);
        acc[2] += bflo(w0.y); acc[3] += bfhi(w0.y);
        acc[4] += bflo(w0.z); acc[5] += bfhi(w0.z);
        acc[6] += bflo(w0.w); acc[7] += bfhi(w0.w);
    }
    // combine the 4 group partials
#pragma unroll
    for (int j = 0; j < 8; ++j) {
        acc[j] += __shfl_xor(acc[j], 16, 64);
        acc[j] += __shfl_xor(acc[j], 32, 64);
    }
    if (lane < 16) {
        int dg = s1 - s0; if (dg < 1) dg = 1;
        float scale = 1.0f / (float)dg;
        ushortx8 o;
#pragma unroll
        for (int j = 0; j < 8; ++j) o[j] = f2bf(acc[j] * scale);
        __builtin_nontemporal_store(o, (ushortx8*)(aggb + (size_t)node * NF + (l16 << 3)));
    }
}

// single fused GEMM: out = relu([feat | agg_n] @ W2 + bias), K=256.
// 512-thread blocks (8 waves share the 64KiB W-tile) -> 2 blocks/CU =
// 16 waves/CU (2x MLP vs 256-thread version). MFMA operands SWAPPED
// (W as A-operand, feat as B-operand): D = (feat*W)^T, so each lane's
// 4 acc regs are 4 consecutive out-cols of its node row -> floatx4 stores.
__global__ __launch_bounds__(512, 4) void k_gemm(
    const unsigned short* __restrict__ featb,
    const unsigned short* __restrict__ aggb,
    const unsigned short* __restrict__ w2t,
    const float* __restrict__ bias,
    float* __restrict__ out) {
    __shared__ unsigned short lds[128 * 256];   // 64 KiB
    for (int i = threadIdx.x; i < 4096; i += 512) {
        ushortx8 w = *(const ushortx8*)(w2t + i * 8);
        *(ushortx8*)(&lds[i * 8]) = w;
    }
    __syncthreads();

    int lane = threadIdx.x & 63;
    int wave = threadIdx.x >> 6;        // 0..7
    int quad = lane >> 4, l15 = lane & 15;

    for (int t = blockIdx.x; t < NTILE2; t += gridDim.x) {
        int rb = t * 128 + wave * 16;
        int arow = rb + l15; if (arow > NN - 1) arow = NN - 1;
        const unsigned short* fr = featb + (size_t)arow * NF;
        const unsigned short* ar = aggb + (size_t)arow * NF;
        bf16x8 a[8];
#pragma unroll
        for (int ks = 0; ks < 4; ++ks) {
            a[ks]     = *(const bf16x8*)(fr + ks * 32 + quad * 8);
            a[4 + ks] = *(const bf16x8*)(ar + ks * 32 + quad * 8);
        }
        floatx4 acc[8];
#pragma unroll
        for (int ct = 0; ct < 8; ++ct) acc[ct] = (floatx4){0.f, 0.f, 0.f, 0.f};
#pragma unroll
        for (int ct = 0; ct < 8; ++ct) {
            int n = ct * 16 + l15;
            int rowoff = n << 8;
            int sw = n & 7;
#pragma unroll
            for (int ks = 0; ks < 8; ++ks) {
                int kg = ks * 4 + quad;
                bf16x8 b = *(const bf16x8*)(&lds[rowoff + ((kg ^ sw) << 3)]);
                // swapped operands: D[outcol][noderow]
                acc[ct] = __builtin_amdgcn_mfma_f32_16x16x32_bf16(b, a[ks], acc[ct], 0, 0, 0);
            }
        }
        int row = rb + l15;
        if (row < NN) {
            float* orow = out + (size_t)row * NF;
#pragma unroll
            for (int ct = 0; ct < 8; ++ct) {
                floatx4 bv = *(const floatx4*)(bias + ct * 16 + quad * 4);
                floatx4 v;
                v.x = acc[ct].x + bv.x; v.y = acc[ct].y + bv.y;
                v.z = acc[ct].z + bv.z; v.w = acc[ct].w + bv.w;
                v.x = v.x > 0.f ? v.x : 0.f;
                v.y = v.y > 0.f ? v.y : 0.f;
                v.z = v.z > 0.f ? v.z : 0.f;
                v.w = v.w > 0.f ? v.w : 0.f;
                *(floatx4*)(orow + ct * 16 + quad * 4) = v;
            }
        }
    }
}

extern "C" void kernel_launch(void* const* d_in, const int* in_sizes, int n_in,
                              void* d_out, int out_size, void* d_ws, size_t ws_size,
                              hipStream_t stream) {
    const float* feat = (const float*)d_in[0];
    const float* wu   = (const float*)d_in[1];
    const float* wv   = (const float*)d_in[2];
    const float* bias = (const float*)d_in[3];
    const int* src    = (const int*)d_in[4];
    const int* dst    = (const int*)d_in[5];
    float* out        = (float*)d_out;

    char* ws = (char*)d_ws;
    int* counts           = (int*)(ws + 0);                    //   800,256 B
    int* bsums            = (int*)(ws + 800256);               //     4,096 B
    int* offs             = (int*)(ws + 804352);               //   400,004 B
    int* csr              = (int*)(ws + 1204480);              // 6,400,000 B
    unsigned short* featb = (unsigned short*)(ws + 7604480);   // 25,600,000 B
    unsigned short* aggb  = (unsigned short*)(ws + 33204480);  // 25,600,000 B
    unsigned short* w2t   = (unsigned short*)(ws + 58804480);  //    65,536 B
    // streams aliases aggb: dead (after k_csr) before k_aggregate writes aggb
    unsigned* streams     = (unsigned*)aggb;                   // 6.4 MB

    k_convert<<<(NN * NF / 4 + 255) / 256, 256, 0, stream>>>(feat, featb, NN * NF / 4);
    k_prep<<<16, 256, 0, stream>>>(wv, wu, w2t);

    k_count<<<NB2, 256, 0, stream>>>(dst, counts);
    k_scan2_a<<<SC2A, 256, 0, stream>>>(counts, bsums);
    k_scan2_b<<<1, 1024, 0, stream>>>(bsums);
    k_scan2_c<<<SC2A, 256, 0, stream>>>(counts, bsums);
    k_binscatter<<<NB2, 256, 0, stream>>>(src, dst, counts, streams);
    k_csr<<<B_BKT, 256, 0, stream>>>(streams, counts, offs, csr);
    k_aggregate<<<(NN + 3) / 4, 256, 0, stream>>>(featb, offs, csr, aggb);
    k_gemm<<<NTILE2, 512, 0, stream>>>(featb, aggb, w2t, bias, out);
}

// Round 3
// 317.253 us; speedup vs baseline: 1.3216x; 1.3216x over previous
//
#include <hip/hip_runtime.h>
#include <hip/hip_bf16.h>
#include <stdint.h>

#define NN 100000
#define NE 1600000
#define NF 128
#define NTILE ((NN + 63) / 64)      // 1563 row tiles of 64 (gemm)
#define GEMM_G 782                  // gemm grid: each block does tiles t, t+782
#define B_BKT 1563                  // 64-node buckets
#define NB2 128                     // binning blocks
#define EPB (NE / NB2)              // 12500 edges per binning block
#define NCNT (B_BKT * NB2)          // 200,064 segment counters
#define SC2A ((NCNT + 255) / 256)   // 782 scan blocks

typedef __attribute__((ext_vector_type(8))) __bf16 bf16x8;
typedef __attribute__((ext_vector_type(4))) float floatx4;
typedef __attribute__((ext_vector_type(4))) unsigned short ushortx4;
typedef __attribute__((ext_vector_type(8))) unsigned short ushortx8;
typedef __attribute__((ext_vector_type(4))) unsigned int uintx4;

static __device__ __forceinline__ unsigned short f2bf(float x) {
    union { float f; unsigned u; } v; v.f = x;
    unsigned r = v.u + 0x7fffu + ((v.u >> 16) & 1u);   // RNE
    return (unsigned short)(r >> 16);
}
static __device__ __forceinline__ float bflo(unsigned w) {
    union { unsigned u; float f; } v; v.u = w << 16; return v.f;
}
static __device__ __forceinline__ float bfhi(unsigned w) {
    union { unsigned u; float f; } v; v.u = w & 0xffff0000u; return v.f;
}

// fp32 -> bf16
__global__ void k_convert(const float* __restrict__ s, unsigned short* __restrict__ d, int n4) {
    int i = blockIdx.x * blockDim.x + threadIdx.x;
    if (i < n4) {
        floatx4 f = __builtin_nontemporal_load((const floatx4*)s + i);
        ushortx4 o;
        o.x = f2bf(f.x); o.y = f2bf(f.y); o.z = f2bf(f.z); o.w = f2bf(f.w);
        __builtin_nontemporal_store(o, (ushortx4*)d + i);
    }
}

// Build W2t: [n][k] bf16, k in 0..255 = [Wv ; Wu], 16B k-chunks XOR-swizzled
__global__ void k_prep(const float* __restrict__ wv, const float* __restrict__ wu,
                       unsigned short* __restrict__ w2t) {
    int id = blockIdx.x * 256 + threadIdx.x;   // 0..4095
    if (id >= 128 * 32) return;
    int n = id >> 5, kg = id & 31;
    const float* srcm = (kg < 16) ? wv : wu;
    int k0 = (kg & 15) * 8;
    ushortx8 o;
#pragma unroll
    for (int j = 0; j < 8; ++j)
        o[j] = f2bf(srcm[(k0 + j) * 128 + n]);
    int dchunk = n * 32 + (kg ^ (n & 7));
    *(ushortx8*)(w2t + dchunk * 8) = o;
}

// pass 1: per-block histogram over 1563 fine buckets (LDS atomics only)
__global__ void k_count(const int* __restrict__ dst, int* __restrict__ counts) {
    __shared__ int h[B_BKT];
    int tid = threadIdx.x;
    for (int i = tid; i < B_BKT; i += 256) h[i] = 0;
    __syncthreads();
    int base = blockIdx.x * EPB, end = base + EPB;
    for (int i = base + tid; i < end; i += 256) {
        int d = __builtin_nontemporal_load(&dst[i]);
        atomicAdd(&h[d >> 6], 1);
    }
    __syncthreads();
    for (int i = tid; i < B_BKT; i += 256)
        counts[i * NB2 + blockIdx.x] = h[i];
}

// hierarchical exclusive scan of the 200,064 counts (bucket-major)
__global__ void k_scan2_a(int* __restrict__ counts, int* __restrict__ bsums) {
    __shared__ int sh[256];
    int i = blockIdx.x * 256 + threadIdx.x;
    int v = (i < NCNT) ? counts[i] : 0;
    sh[threadIdx.x] = v;
    __syncthreads();
    for (int off = 1; off < 256; off <<= 1) {
        int u = (threadIdx.x >= off) ? sh[threadIdx.x - off] : 0;
        __syncthreads();
        sh[threadIdx.x] += u;
        __syncthreads();
    }
    if (i < NCNT) counts[i] = sh[threadIdx.x] - v;
    if (threadIdx.x == 255) bsums[blockIdx.x] = sh[255];
}
__global__ void k_scan2_b(int* __restrict__ bsums) {
    __shared__ int sh[1024];
    int t = threadIdx.x;
    int v = (t < SC2A) ? bsums[t] : 0;
    sh[t] = v;
    __syncthreads();
    for (int off = 1; off < 1024; off <<= 1) {
        int u = (t >= off) ? sh[t - off] : 0;
        __syncthreads();
        sh[t] += u;
        __syncthreads();
    }
    if (t < SC2A) bsums[t] = sh[t] - v;
}
__global__ void k_scan2_c(int* __restrict__ counts, const int* __restrict__ bsums) {
    int i = blockIdx.x * 256 + threadIdx.x;
    if (i < NCNT) counts[i] += bsums[blockIdx.x];
}

// pass 2: deterministic scatter into bucket-sorted stream; LDS cursors only
__global__ void k_binscatter(const int* __restrict__ src, const int* __restrict__ dst,
                             const int* __restrict__ counts, unsigned* __restrict__ streams) {
    __shared__ int cur[B_BKT];
    int tid = threadIdx.x;
    for (int i = tid; i < B_BKT; i += 256)
        cur[i] = counts[i * NB2 + blockIdx.x];
    __syncthreads();
    int base = blockIdx.x * EPB, end = base + EPB;
    for (int i = base + tid; i < end; i += 256) {
        int d = __builtin_nontemporal_load(&dst[i]);
        int s = __builtin_nontemporal_load(&src[i]);
        int b = d >> 6;
        unsigned packed = ((unsigned)(d & 63) << 17) | (unsigned)s;
        int pos = atomicAdd(&cur[b], 1);
        streams[pos] = packed;
    }
}

// finalize CSR per bucket: histogram 64 nodes, tiny serial scan, write offs,
// scatter src into the block's OWN contiguous [s,e) csr range
__global__ void k_csr(const unsigned* __restrict__ streams,
                      const int* __restrict__ counts,
                      int* __restrict__ offs, int* __restrict__ csr) {
    __shared__ int hist[64];
    __shared__ int nodeoff[65];
    int tid = threadIdx.x;
    int bkt = blockIdx.x;
    int s = counts[bkt * NB2];
    int e = (bkt == B_BKT - 1) ? NE : counts[(bkt + 1) * NB2];
    if (tid < 64) hist[tid] = 0;
    __syncthreads();
    for (int i = s + tid; i < e; i += 256)
        atomicAdd(&hist[streams[i] >> 17], 1);
    __syncthreads();
    if (tid == 0) {
        int run = 0;
#pragma unroll
        for (int n = 0; n < 64; ++n) { nodeoff[n] = run; run += hist[n]; }
        nodeoff[64] = run;
    }
    __syncthreads();
    if (tid < 64) {
        int node = bkt * 64 + tid;
        if (node < NN) offs[node] = s + nodeoff[tid];
        hist[tid] = nodeoff[tid];          // reuse as relative cursor
    }
    if (bkt == B_BKT - 1 && tid == 0) offs[NN] = NE;
    __syncthreads();
    for (int i = s + tid; i < e; i += 256) {
        unsigned v = streams[i];
        int p = atomicAdd(&hist[v >> 17], 1);
        csr[s + p] = (int)(v & 0x1FFFFu);
    }
}

// one wave per node. 4 lane-groups of 16; each group owns one edge per step,
// each lane loads 16B (8 feats) of the row -> 4 edges per load instruction.
__global__ void k_aggregate(const unsigned short* __restrict__ featb,
                            const int* __restrict__ offs,
                            const int* __restrict__ csr,
                            unsigned short* __restrict__ aggb) {
    int lane = threadIdx.x & 63;
    int node = blockIdx.x * 4 + (threadIdx.x >> 6);
    if (node >= NN) return;
    int g = lane >> 4;        // edge subgroup 0..3
    int l16 = lane & 15;      // feat chunk: 8 feats at l16*8
    int s0 = offs[node], s1 = offs[node + 1];
    float acc[8];
#pragma unroll
    for (int j = 0; j < 8; ++j) acc[j] = 0.f;

    int base = s0 + g;
    // main loop: 8 edges per wave iteration (2 per group), independent loads
    for (; base + 4 < s1; base += 8) {
        int e0 = __builtin_nontemporal_load(&csr[base]);
        int e1 = __builtin_nontemporal_load(&csr[base + 4]);
        uintx4 w0 = *(const uintx4*)(featb + (e0 << 7) + (l16 << 3));
        uintx4 w1 = *(const uintx4*)(featb + (e1 << 7) + (l16 << 3));
        acc[0] += bflo(w0.x); acc[1] += bfhi(w0.x);
        acc[2] += bflo(w0.y); acc[3] += bfhi(w0.y);
        acc[4] += bflo(w0.z); acc[5] += bfhi(w0.z);
        acc[6] += bflo(w0.w); acc[7] += bfhi(w0.w);
        acc[0] += bflo(w1.x); acc[1] += bfhi(w1.x);
        acc[2] += bflo(w1.y); acc[3] += bfhi(w1.y);
        acc[4] += bflo(w1.z); acc[5] += bfhi(w1.z);
        acc[6] += bflo(w1.w); acc[7] += bfhi(w1.w);
    }
    if (base < s1) {           // remainder: at most one edge per group
        int e0 = __builtin_nontemporal_load(&csr[base]);
        uintx4 w0 = *(const uintx4*)(featb + (e0 << 7) + (l16 << 3));
        acc[0] += bflo(w0.x); acc[1] += bfhi(w0.x);
        acc[2] += bflo(w0.y); acc[3] += bfhi(w0.y);
        acc[4] += bflo(w0.z); acc[5] += bfhi(w0.z);
        acc[6] += bflo(w0.w); acc[7] += bfhi(w0.w);
    }
    // combine the 4 group partials
#pragma unroll
    for (int j = 0; j < 8; ++j) {
        acc[j] += __shfl_xor(acc[j], 16, 64);
        acc[j] += __shfl_xor(acc[j], 32, 64);
    }
    if (lane < 16) {
        int dg = s1 - s0; if (dg < 1) dg = 1;
        float scale = 1.0f / (float)dg;
        ushortx8 o;
#pragma unroll
        for (int j = 0; j < 8; ++j) o[j] = f2bf(acc[j] * scale);
        __builtin_nontemporal_store(o, (ushortx8*)(aggb + (size_t)node * NF + (l16 << 3)));
    }
}

// MFMA + epilogue for one 64-row tile (A-fragments already loaded)
static __device__ __forceinline__ void gemm_tile(
    const unsigned short* lds, const bf16x8* a, const float* bsv,
    int rb, int quad, int l15, float* __restrict__ out) {
    floatx4 acc[8];
#pragma unroll
    for (int ct = 0; ct < 8; ++ct) acc[ct] = (floatx4){0.f, 0.f, 0.f, 0.f};
#pragma unroll
    for (int ct = 0; ct < 8; ++ct) {
        int n = ct * 16 + l15;
        int rowoff = n << 8;
        int sw = n & 7;
#pragma unroll
        for (int ks = 0; ks < 8; ++ks) {
            int kg = ks * 4 + quad;
            bf16x8 b = *(const bf16x8*)(&lds[rowoff + ((kg ^ sw) << 3)]);
            acc[ct] = __builtin_amdgcn_mfma_f32_16x16x32_bf16(a[ks], b, acc[ct], 0, 0, 0);
        }
    }
#pragma unroll
    for (int r = 0; r < 4; ++r) {
        int row = rb + quad * 4 + r;
        if (row < NN) {
#pragma unroll
            for (int ct = 0; ct < 8; ++ct) {
                int col = ct * 16 + l15;
                float v = acc[ct][r] + bsv[ct];
                out[(size_t)row * NF + col] = v > 0.f ? v : 0.f;
            }
        }
    }
}

// single fused GEMM: out = relu([feat | agg_n] @ W2 + bias), K=256.
// 256-thr blocks (64KiB W-tile -> 2 blocks/CU). Each block owns two tiles
// (t, t+GEMM_G); tile-2's 8 A-loads are issued BEFORE tile-1's MFMA so each
// wave keeps 16 global loads in flight (2x MLP vs the grid-stride version;
// the gather is latency-bound, proven by round-2's occupancy->BW response).
__global__ __launch_bounds__(256, 2) void k_gemm(
    const unsigned short* __restrict__ featb,
    const unsigned short* __restrict__ aggb,
    const unsigned short* __restrict__ w2t,
    const float* __restrict__ bias,
    float* __restrict__ out) {
    __shared__ unsigned short lds[128 * 256];   // 64 KiB
    for (int i = threadIdx.x; i < 4096; i += 256) {
        ushortx8 w = *(const ushortx8*)(w2t + i * 8);
        *(ushortx8*)(&lds[i * 8]) = w;
    }
    __syncthreads();

    int lane = threadIdx.x & 63;
    int wave = threadIdx.x >> 6;
    int quad = lane >> 4, l15 = lane & 15;

    float bsv[8];
#pragma unroll
    for (int ct = 0; ct < 8; ++ct) bsv[ct] = bias[ct * 16 + l15];

    int t0 = blockIdx.x;
    int t1 = t0 + GEMM_G;                    // may be >= NTILE (last block)
    int t1v = (t1 < NTILE) ? t1 : t0;        // safe address for the prefetch

    int rb0 = t0 * 64 + wave * 16;
    int rb1 = t1v * 64 + wave * 16;
    int ar0 = rb0 + l15; if (ar0 > NN - 1) ar0 = NN - 1;
    int ar1 = rb1 + l15; if (ar1 > NN - 1) ar1 = NN - 1;
    const unsigned short* fr0 = featb + (size_t)ar0 * NF;
    const unsigned short* ag0 = aggb + (size_t)ar0 * NF;
    const unsigned short* fr1 = featb + (size_t)ar1 * NF;
    const unsigned short* ag1 = aggb + (size_t)ar1 * NF;

    bf16x8 a0[8], a1[8];
#pragma unroll
    for (int ks = 0; ks < 4; ++ks) {         // tile-1 A-fragments
        a0[ks]     = *(const bf16x8*)(fr0 + ks * 32 + quad * 8);
        a0[4 + ks] = *(const bf16x8*)(ag0 + ks * 32 + quad * 8);
    }
#pragma unroll
    for (int ks = 0; ks < 4; ++ks) {         // tile-2 prefetch, in flight
        a1[ks]     = *(const bf16x8*)(fr1 + ks * 32 + quad * 8);
        a1[4 + ks] = *(const bf16x8*)(ag1 + ks * 32 + quad * 8);
    }

    gemm_tile(lds, a0, bsv, rb0, quad, l15, out);
    if (t1 < NTILE)
        gemm_tile(lds, a1, bsv, rb1, quad, l15, out);
}

extern "C" void kernel_launch(void* const* d_in, const int* in_sizes, int n_in,
                              void* d_out, int out_size, void* d_ws, size_t ws_size,
                              hipStream_t stream) {
    const float* feat = (const float*)d_in[0];
    const float* wu   = (const float*)d_in[1];
    const float* wv   = (const float*)d_in[2];
    const float* bias = (const float*)d_in[3];
    const int* src    = (const int*)d_in[4];
    const int* dst    = (const int*)d_in[5];
    float* out        = (float*)d_out;

    char* ws = (char*)d_ws;
    int* counts           = (int*)(ws + 0);                    //   800,256 B
    int* bsums            = (int*)(ws + 800256);               //     4,096 B
    int* offs             = (int*)(ws + 804352);               //   400,004 B
    int* csr              = (int*)(ws + 1204480);              // 6,400,000 B
    unsigned short* featb = (unsigned short*)(ws + 7604480);   // 25,600,000 B
    unsigned short* aggb  = (unsigned short*)(ws + 33204480);  // 25,600,000 B
    unsigned short* w2t   = (unsigned short*)(ws + 58804480);  //    65,536 B
    // streams aliases aggb: dead (after k_csr) before k_aggregate writes aggb
    unsigned* streams     = (unsigned*)aggb;                   // 6.4 MB

    k_convert<<<(NN * NF / 4 + 255) / 256, 256, 0, stream>>>(feat, featb, NN * NF / 4);
    k_prep<<<16, 256, 0, stream>>>(wv, wu, w2t);

    k_count<<<NB2, 256, 0, stream>>>(dst, counts);
    k_scan2_a<<<SC2A, 256, 0, stream>>>(counts, bsums);
    k_scan2_b<<<1, 1024, 0, stream>>>(bsums);
    k_scan2_c<<<SC2A, 256, 0, stream>>>(counts, bsums);
    k_binscatter<<<NB2, 256, 0, stream>>>(src, dst, counts, streams);
    k_csr<<<B_BKT, 256, 0, stream>>>(streams, counts, offs, csr);
    k_aggregate<<<(NN + 3) / 4, 256, 0, stream>>>(featb, offs, csr, aggb);
    k_gemm<<<GEMM_G, 256, 0, stream>>>(featb, aggb, w2t, bias, out);
}

// Round 4
// 310.718 us; speedup vs baseline: 1.3494x; 1.0210x over previous
//
#include <hip/hip_runtime.h>
#include <hip/hip_bf16.h>
#include <stdint.h>

#define NN 100000
#define NE 1600000
#define NF 128
#define NTILE ((NN + 63) / 64)      // 1563 row tiles of 64 (gemm)
#define GEMM_G 782                  // gemm grid: each block does tiles t, t+782
#define B_BKT 1563                  // 64-node buckets
#define NB2 128                     // binning blocks
#define EPB (NE / NB2)              // 12500 edges per binning block
#define NCNT (B_BKT * NB2)          // 200,064 segment counters
#define SC2A ((NCNT + 255) / 256)   // 782 scan blocks

typedef __attribute__((ext_vector_type(8))) __bf16 bf16x8;
typedef __attribute__((ext_vector_type(4))) float floatx4;
typedef __attribute__((ext_vector_type(4))) unsigned short ushortx4;
typedef __attribute__((ext_vector_type(8))) unsigned short ushortx8;
typedef __attribute__((ext_vector_type(4))) unsigned int uintx4;

static __device__ __forceinline__ unsigned short f2bf(float x) {
    union { float f; unsigned u; } v; v.f = x;
    unsigned r = v.u + 0x7fffu + ((v.u >> 16) & 1u);   // RNE
    return (unsigned short)(r >> 16);
}
static __device__ __forceinline__ float bflo(unsigned w) {
    union { unsigned u; float f; } v; v.u = w << 16; return v.f;
}
static __device__ __forceinline__ float bfhi(unsigned w) {
    union { unsigned u; float f; } v; v.u = w & 0xffff0000u; return v.f;
}

// fp32 -> bf16
__global__ void k_convert(const float* __restrict__ s, unsigned short* __restrict__ d, int n4) {
    int i = blockIdx.x * blockDim.x + threadIdx.x;
    if (i < n4) {
        floatx4 f = __builtin_nontemporal_load((const floatx4*)s + i);
        ushortx4 o;
        o.x = f2bf(f.x); o.y = f2bf(f.y); o.z = f2bf(f.z); o.w = f2bf(f.w);
        __builtin_nontemporal_store(o, (ushortx4*)d + i);
    }
}

// Build W2t: [n][k] bf16, k in 0..255 = [Wv ; Wu], 16B k-chunks XOR-swizzled
__global__ void k_prep(const float* __restrict__ wv, const float* __restrict__ wu,
                       unsigned short* __restrict__ w2t) {
    int id = blockIdx.x * 256 + threadIdx.x;   // 0..4095
    if (id >= 128 * 32) return;
    int n = id >> 5, kg = id & 31;
    const float* srcm = (kg < 16) ? wv : wu;
    int k0 = (kg & 15) * 8;
    ushortx8 o;
#pragma unroll
    for (int j = 0; j < 8; ++j)
        o[j] = f2bf(srcm[(k0 + j) * 128 + n]);
    int dchunk = n * 32 + (kg ^ (n & 7));
    *(ushortx8*)(w2t + dchunk * 8) = o;
}

// pass 1: per-block histogram over 1563 fine buckets (LDS atomics only)
// 512 threads: grid is only 128 blocks (half the CUs), so widen each block.
__global__ void k_count(const int* __restrict__ dst, int* __restrict__ counts) {
    __shared__ int h[B_BKT];
    int tid = threadIdx.x;
    for (int i = tid; i < B_BKT; i += 512) h[i] = 0;
    __syncthreads();
    int base = blockIdx.x * EPB, end = base + EPB;
    for (int i = base + tid; i < end; i += 512) {
        int d = __builtin_nontemporal_load(&dst[i]);
        atomicAdd(&h[d >> 6], 1);
    }
    __syncthreads();
    for (int i = tid; i < B_BKT; i += 512)
        counts[i * NB2 + blockIdx.x] = h[i];
}

// hierarchical exclusive scan of the 200,064 counts (bucket-major).
// counts[i] becomes block-local exclusive prefix; bsums[j] the block totals.
// Consumers add bsums[i>>8] on the fly (no third fixup pass needed).
__global__ void k_scan2_a(int* __restrict__ counts, int* __restrict__ bsums) {
    __shared__ int sh[256];
    int i = blockIdx.x * 256 + threadIdx.x;
    int v = (i < NCNT) ? counts[i] : 0;
    sh[threadIdx.x] = v;
    __syncthreads();
    for (int off = 1; off < 256; off <<= 1) {
        int u = (threadIdx.x >= off) ? sh[threadIdx.x - off] : 0;
        __syncthreads();
        sh[threadIdx.x] += u;
        __syncthreads();
    }
    if (i < NCNT) counts[i] = sh[threadIdx.x] - v;
    if (threadIdx.x == 255) bsums[blockIdx.x] = sh[255];
}
__global__ void k_scan2_b(int* __restrict__ bsums) {
    __shared__ int sh[1024];
    int t = threadIdx.x;
    int v = (t < SC2A) ? bsums[t] : 0;
    sh[t] = v;
    __syncthreads();
    for (int off = 1; off < 1024; off <<= 1) {
        int u = (t >= off) ? sh[t - off] : 0;
        __syncthreads();
        sh[t] += u;
        __syncthreads();
    }
    if (t < SC2A) bsums[t] = sh[t] - v;
}

// pass 2: deterministic scatter into bucket-sorted stream; LDS cursors only.
// 512 threads (grid 128). Cursor init folds in the scan block offset.
__global__ void k_binscatter(const int* __restrict__ src, const int* __restrict__ dst,
                             const int* __restrict__ counts, const int* __restrict__ bsums,
                             unsigned* __restrict__ streams) {
    __shared__ int cur[B_BKT];
    int tid = threadIdx.x;
    for (int i = tid; i < B_BKT; i += 512) {
        int idx = i * NB2 + blockIdx.x;
        cur[i] = counts[idx] + bsums[idx >> 8];
    }
    __syncthreads();
    int base = blockIdx.x * EPB, end = base + EPB;
    for (int i = base + tid; i < end; i += 512) {
        int d = __builtin_nontemporal_load(&dst[i]);
        int s = __builtin_nontemporal_load(&src[i]);
        int b = d >> 6;
        unsigned packed = ((unsigned)(d & 63) << 17) | (unsigned)s;
        int pos = atomicAdd(&cur[b], 1);
        streams[pos] = packed;
    }
}

// finalize CSR per bucket: histogram 64 nodes, tiny serial scan, write offs,
// scatter src into the block's OWN contiguous [s,e) csr range
__global__ void k_csr(const unsigned* __restrict__ streams,
                      const int* __restrict__ counts, const int* __restrict__ bsums,
                      int* __restrict__ offs, int* __restrict__ csr) {
    __shared__ int hist[64];
    __shared__ int nodeoff[65];
    int tid = threadIdx.x;
    int bkt = blockIdx.x;
    int idx = bkt * NB2;
    int s = counts[idx] + bsums[idx >> 8];
    int e = (bkt == B_BKT - 1) ? NE : (counts[idx + NB2] + bsums[(idx + NB2) >> 8]);
    if (tid < 64) hist[tid] = 0;
    __syncthreads();
    for (int i = s + tid; i < e; i += 256)
        atomicAdd(&hist[streams[i] >> 17], 1);
    __syncthreads();
    if (tid == 0) {
        int run = 0;
#pragma unroll
        for (int n = 0; n < 64; ++n) { nodeoff[n] = run; run += hist[n]; }
        nodeoff[64] = run;
    }
    __syncthreads();
    if (tid < 64) {
        int node = bkt * 64 + tid;
        if (node < NN) offs[node] = s + nodeoff[tid];
        hist[tid] = nodeoff[tid];          // reuse as relative cursor
    }
    if (bkt == B_BKT - 1 && tid == 0) offs[NN] = NE;
    __syncthreads();
    for (int i = s + tid; i < e; i += 256) {
        unsigned v = streams[i];
        int p = atomicAdd(&hist[v >> 17], 1);
        csr[s + p] = (int)(v & 0x1FFFFu);
    }
}

// one wave per node, 4 lane-groups of 16, one edge per group per stage,
// depth-3 software pipeline: the row load for stage k+3 is issued before
// stage k is consumed -> 3 rows/group (12/wave) in flight regardless of
// compiler scheduling. Exec-masked loads handle the per-group tail.
__global__ void k_aggregate(const unsigned short* __restrict__ featb,
                            const int* __restrict__ offs,
                            const int* __restrict__ csr,
                            unsigned short* __restrict__ aggb) {
    int lane = threadIdx.x & 63;
    int node = blockIdx.x * 4 + (threadIdx.x >> 6);
    if (node >= NN) return;
    int g = lane >> 4;        // edge subgroup 0..3
    int fo = (lane & 15) << 3; // feat chunk: 8 feats
    int s0 = offs[node], s1 = offs[node + 1];
    float acc[8];
#pragma unroll
    for (int j = 0; j < 8; ++j) acc[j] = 0.f;

    uintx4 w0 = (uintx4){0,0,0,0}, w1 = w0, w2 = w0;
    int P = s0 + g;
    if (P < s1) {
        int c = __builtin_nontemporal_load(&csr[P]);
        w0 = *(const uintx4*)(featb + ((size_t)c << 7) + fo);
    }
    if (P + 4 < s1) {
        int c = __builtin_nontemporal_load(&csr[P + 4]);
        w1 = *(const uintx4*)(featb + ((size_t)c << 7) + fo);
    }
    if (P + 8 < s1) {
        int c = __builtin_nontemporal_load(&csr[P + 8]);
        w2 = *(const uintx4*)(featb + ((size_t)c << 7) + fo);
    }
    int Pn = P + 12;
    for (int pp = s0; pp < s1; pp += 4) {
        uintx4 cw = w0;
        w0 = w1; w1 = w2;
        w2 = (uintx4){0,0,0,0};
        if (Pn < s1) {                       // fetch stage k+3 first
            int c = __builtin_nontemporal_load(&csr[Pn]);
            w2 = *(const uintx4*)(featb + ((size_t)c << 7) + fo);
        }
        Pn += 4;
        acc[0] += bflo(cw.x); acc[1] += bfhi(cw.x);
        acc[2] += bflo(cw.y); acc[3] += bfhi(cw.y);
        acc[4] += bflo(cw.z); acc[5] += bfhi(cw.z);
        acc[6] += bflo(cw.w); acc[7] += bfhi(cw.w);
    }
    // combine the 4 group partials
#pragma unroll
    for (int j = 0; j < 8; ++j) {
        acc[j] += __shfl_xor(acc[j], 16, 64);
        acc[j] += __shfl_xor(acc[j], 32, 64);
    }
    if (lane < 16) {
        int dg = s1 - s0; if (dg < 1) dg = 1;
        float scale = 1.0f / (float)dg;
        ushortx8 o;
#pragma unroll
        for (int j = 0; j < 8; ++j) o[j] = f2bf(acc[j] * scale);
        __builtin_nontemporal_store(o, (ushortx8*)(aggb + (size_t)node * NF + fo));
    }
}

// MFMA + epilogue for one 64-row tile (A-fragments already loaded)
static __device__ __forceinline__ void gemm_tile(
    const unsigned short* lds, const bf16x8* a, const float* bsv,
    int rb, int quad, int l15, float* __restrict__ out) {
    floatx4 acc[8];
#pragma unroll
    for (int ct = 0; ct < 8; ++ct) acc[ct] = (floatx4){0.f, 0.f, 0.f, 0.f};
#pragma unroll
    for (int ct = 0; ct < 8; ++ct) {
        int n = ct * 16 + l15;
        int rowoff = n << 8;
        int sw = n & 7;
#pragma unroll
        for (int ks = 0; ks < 8; ++ks) {
            int kg = ks * 4 + quad;
            bf16x8 b = *(const bf16x8*)(&lds[rowoff + ((kg ^ sw) << 3)]);
            acc[ct] = __builtin_amdgcn_mfma_f32_16x16x32_bf16(a[ks], b, acc[ct], 0, 0, 0);
        }
    }
#pragma unroll
    for (int r = 0; r < 4; ++r) {
        int row = rb + quad * 4 + r;
        if (row < NN) {
#pragma unroll
            for (int ct = 0; ct < 8; ++ct) {
                int col = ct * 16 + l15;
                float v = acc[ct][r] + bsv[ct];
                out[(size_t)row * NF + col] = v > 0.f ? v : 0.f;
            }
        }
    }
}

// single fused GEMM: out = relu([feat | agg_n] @ W2 + bias), K=256.
// 256-thr blocks (64KiB W-tile -> 2 blocks/CU). Each block owns two tiles
// (t, t+GEMM_G); tile-2's 8 A-loads are issued BEFORE tile-1's MFMA so each
// wave keeps 16 global loads in flight.
__global__ __launch_bounds__(256, 2) void k_gemm(
    const unsigned short* __restrict__ featb,
    const unsigned short* __restrict__ aggb,
    const unsigned short* __restrict__ w2t,
    const float* __restrict__ bias,
    float* __restrict__ out) {
    __shared__ unsigned short lds[128 * 256];   // 64 KiB
    for (int i = threadIdx.x; i < 4096; i += 256) {
        ushortx8 w = *(const ushortx8*)(w2t + i * 8);
        *(ushortx8*)(&lds[i * 8]) = w;
    }
    __syncthreads();

    int lane = threadIdx.x & 63;
    int wave = threadIdx.x >> 6;
    int quad = lane >> 4, l15 = lane & 15;

    float bsv[8];
#pragma unroll
    for (int ct = 0; ct < 8; ++ct) bsv[ct] = bias[ct * 16 + l15];

    int t0 = blockIdx.x;
    int t1 = t0 + GEMM_G;                    // may be >= NTILE (last block)
    int t1v = (t1 < NTILE) ? t1 : t0;        // safe address for the prefetch

    int rb0 = t0 * 64 + wave * 16;
    int rb1 = t1v * 64 + wave * 16;
    int ar0 = rb0 + l15; if (ar0 > NN - 1) ar0 = NN - 1;
    int ar1 = rb1 + l15; if (ar1 > NN - 1) ar1 = NN - 1;
    const unsigned short* fr0 = featb + (size_t)ar0 * NF;
    const unsigned short* ag0 = aggb + (size_t)ar0 * NF;
    const unsigned short* fr1 = featb + (size_t)ar1 * NF;
    const unsigned short* ag1 = aggb + (size_t)ar1 * NF;

    bf16x8 a0[8], a1[8];
#pragma unroll
    for (int ks = 0; ks < 4; ++ks) {         // tile-1 A-fragments
        a0[ks]     = *(const bf16x8*)(fr0 + ks * 32 + quad * 8);
        a0[4 + ks] = *(const bf16x8*)(ag0 + ks * 32 + quad * 8);
    }
#pragma unroll
    for (int ks = 0; ks < 4; ++ks) {         // tile-2 prefetch, in flight
        a1[ks]     = *(const bf16x8*)(fr1 + ks * 32 + quad * 8);
        a1[4 + ks] = *(const bf16x8*)(ag1 + ks * 32 + quad * 8);
    }

    gemm_tile(lds, a0, bsv, rb0, quad, l15, out);
    if (t1 < NTILE)
        gemm_tile(lds, a1, bsv, rb1, quad, l15, out);
}

extern "C" void kernel_launch(void* const* d_in, const int* in_sizes, int n_in,
                              void* d_out, int out_size, void* d_ws, size_t ws_size,
                              hipStream_t stream) {
    const float* feat = (const float*)d_in[0];
    const float* wu   = (const float*)d_in[1];
    const float* wv   = (const float*)d_in[2];
    const float* bias = (const float*)d_in[3];
    const int* src    = (const int*)d_in[4];
    const int* dst    = (const int*)d_in[5];
    float* out        = (float*)d_out;

    char* ws = (char*)d_ws;
    int* counts           = (int*)(ws + 0);                    //   800,256 B
    int* bsums            = (int*)(ws + 800256);               //     4,096 B
    int* offs             = (int*)(ws + 804352);               //   400,004 B
    int* csr              = (int*)(ws + 1204480);              // 6,400,000 B
    unsigned short* featb = (unsigned short*)(ws + 7604480);   // 25,600,000 B
    unsigned short* aggb  = (unsigned short*)(ws + 33204480);  // 25,600,000 B
    unsigned short* w2t   = (unsigned short*)(ws + 58804480);  //    65,536 B
    // streams aliases aggb: dead (after k_csr) before k_aggregate writes aggb
    unsigned* streams     = (unsigned*)aggb;                   // 6.4 MB

    k_convert<<<(NN * NF / 4 + 255) / 256, 256, 0, stream>>>(feat, featb, NN * NF / 4);
    k_prep<<<16, 256, 0, stream>>>(wv, wu, w2t);

    k_count<<<NB2, 512, 0, stream>>>(dst, counts);
    k_scan2_a<<<SC2A, 256, 0, stream>>>(counts, bsums);
    k_scan2_b<<<1, 1024, 0, stream>>>(bsums);
    k_binscatter<<<NB2, 512, 0, stream>>>(src, dst, counts, bsums, streams);
    k_csr<<<B_BKT, 256, 0, stream>>>(streams, counts, bsums, offs, csr);
    k_aggregate<<<(NN + 3) / 4, 256, 0, stream>>>(featb, offs, csr, aggb);
    k_gemm<<<GEMM_G, 256, 0, stream>>>(featb, aggb, w2t, bias, out);
}

// Round 5
// 295.126 us; speedup vs baseline: 1.4207x; 1.0528x over previous
//
#include <hip/hip_runtime.h>
#include <hip/hip_bf16.h>
#include <stdint.h>

#define NN 100000
#define NE 1600000
#define NF 128
#define NTILE ((NN + 63) / 64)      // 1563 row tiles of 64 (gemm)
#define GEMM_G 782                  // gemm grid: each block does tiles t, t+782
#define B_BKT 1563                  // 64-node buckets
#define NB2 128                     // binning blocks
#define EPB (NE / NB2)              // 12500 edges per binning block
#define NCNT (B_BKT * NB2)          // 200,064 segment counters
#define SC2A ((NCNT + 255) / 256)   // 782 scan blocks
#define CONV4 (NN * NF / 4)         // 3.2M float4 groups for convert
#define CONV_BLK ((CONV4 + 255) / 256)   // 12500
#define SETUP_GRID (NB2 + 16 + CONV_BLK) // count | prep | convert

typedef __attribute__((ext_vector_type(8))) __bf16 bf16x8;
typedef __attribute__((ext_vector_type(4))) float floatx4;
typedef __attribute__((ext_vector_type(4))) unsigned short ushortx4;
typedef __attribute__((ext_vector_type(8))) unsigned short ushortx8;

static __device__ __forceinline__ unsigned short f2bf(float x) {
    union { float f; unsigned u; } v; v.f = x;
    unsigned r = v.u + 0x7fffu + ((v.u >> 16) & 1u);   // RNE
    return (unsigned short)(r >> 16);
}
static __device__ __forceinline__ float bflo(unsigned w) {
    union { unsigned u; float f; } v; v.u = w << 16; return v.f;
}
static __device__ __forceinline__ float bfhi(unsigned w) {
    union { unsigned u; float f; } v; v.u = w & 0xffff0000u; return v.f;
}

// Fused setup: blocks [0,NB2) histogram dst into 1563 fine buckets;
// blocks [NB2,NB2+16) build the swizzled W2t; the rest convert feat->bf16.
// The three parts are independent; fusing overlaps count's LDS-atomic phase
// with convert's HBM-bound phase and removes two stream-serialized launches.
__global__ void k_setup(const float* __restrict__ feat, unsigned short* __restrict__ featb,
                        const float* __restrict__ wv, const float* __restrict__ wu,
                        unsigned short* __restrict__ w2t,
                        const int* __restrict__ dst, int* __restrict__ counts) {
    __shared__ int h[B_BKT];
    int b = blockIdx.x;
    int tid = threadIdx.x;
    if (b < NB2) {                       // ---- count ----
        for (int i = tid; i < B_BKT; i += 256) h[i] = 0;
        __syncthreads();
        int base = b * EPB, end = base + EPB;
        for (int i = base + tid; i < end; i += 256) {
            int d = __builtin_nontemporal_load(&dst[i]);
            atomicAdd(&h[d >> 6], 1);
        }
        __syncthreads();
        for (int i = tid; i < B_BKT; i += 256)
            counts[i * NB2 + b] = h[i];
    } else if (b < NB2 + 16) {           // ---- prep W2t ----
        int id = (b - NB2) * 256 + tid;  // 0..4095
        if (id < 128 * 32) {
            int n = id >> 5, kg = id & 31;
            const float* srcm = (kg < 16) ? wv : wu;
            int k0 = (kg & 15) * 8;
            ushortx8 o;
#pragma unroll
            for (int j = 0; j < 8; ++j)
                o[j] = f2bf(srcm[(k0 + j) * 128 + n]);
            int dchunk = n * 32 + (kg ^ (n & 7));
            *(ushortx8*)(w2t + dchunk * 8) = o;
        }
    } else {                             // ---- convert fp32 -> bf16 ----
        int i = (b - NB2 - 16) * 256 + tid;
        if (i < CONV4) {
            floatx4 f = __builtin_nontemporal_load((const floatx4*)feat + i);
            ushortx4 o;
            o.x = f2bf(f.x); o.y = f2bf(f.y); o.z = f2bf(f.z); o.w = f2bf(f.w);
            __builtin_nontemporal_store(o, (ushortx4*)featb + i);
        }
    }
}

// hierarchical exclusive scan of the 200,064 counts (bucket-major).
// counts[i] becomes block-local exclusive prefix; bsums[j] the block totals.
// Consumers add bsums[i>>8] on the fly (no third fixup pass needed).
__global__ void k_scan2_a(int* __restrict__ counts, int* __restrict__ bsums) {
    __shared__ int sh[256];
    int i = blockIdx.x * 256 + threadIdx.x;
    int v = (i < NCNT) ? counts[i] : 0;
    sh[threadIdx.x] = v;
    __syncthreads();
    for (int off = 1; off < 256; off <<= 1) {
        int u = (threadIdx.x >= off) ? sh[threadIdx.x - off] : 0;
        __syncthreads();
        sh[threadIdx.x] += u;
        __syncthreads();
    }
    if (i < NCNT) counts[i] = sh[threadIdx.x] - v;
    if (threadIdx.x == 255) bsums[blockIdx.x] = sh[255];
}
__global__ void k_scan2_b(int* __restrict__ bsums) {
    __shared__ int sh[1024];
    int t = threadIdx.x;
    int v = (t < SC2A) ? bsums[t] : 0;
    sh[t] = v;
    __syncthreads();
    for (int off = 1; off < 1024; off <<= 1) {
        int u = (t >= off) ? sh[t - off] : 0;
        __syncthreads();
        sh[t] += u;
        __syncthreads();
    }
    if (t < SC2A) bsums[t] = sh[t] - v;
}

// pass 2: deterministic scatter into bucket-sorted stream; LDS cursors only.
// 512 threads (grid 128). Cursor init folds in the scan block offset.
__global__ void k_binscatter(const int* __restrict__ src, const int* __restrict__ dst,
                             const int* __restrict__ counts, const int* __restrict__ bsums,
                             unsigned* __restrict__ streams) {
    __shared__ int cur[B_BKT];
    int tid = threadIdx.x;
    for (int i = tid; i < B_BKT; i += 512) {
        int idx = i * NB2 + blockIdx.x;
        cur[i] = counts[idx] + bsums[idx >> 8];
    }
    __syncthreads();
    int base = blockIdx.x * EPB, end = base + EPB;
    for (int i = base + tid; i < end; i += 512) {
        int d = __builtin_nontemporal_load(&dst[i]);
        int s = __builtin_nontemporal_load(&src[i]);
        int b = d >> 6;
        unsigned packed = ((unsigned)(d & 63) << 17) | (unsigned)s;
        int pos = atomicAdd(&cur[b], 1);
        streams[pos] = packed;
    }
}

// finalize CSR per bucket: histogram 64 nodes, tiny serial scan, write offs,
// scatter src into the block's OWN contiguous [s,e) csr range
__global__ void k_csr(const unsigned* __restrict__ streams,
                      const int* __restrict__ counts, const int* __restrict__ bsums,
                      int* __restrict__ offs, int* __restrict__ csr) {
    __shared__ int hist[64];
    __shared__ int nodeoff[65];
    int tid = threadIdx.x;
    int bkt = blockIdx.x;
    int idx = bkt * NB2;
    int s = counts[idx] + bsums[idx >> 8];
    int e = (bkt == B_BKT - 1) ? NE : (counts[idx + NB2] + bsums[(idx + NB2) >> 8]);
    if (tid < 64) hist[tid] = 0;
    __syncthreads();
    for (int i = s + tid; i < e; i += 256)
        atomicAdd(&hist[streams[i] >> 17], 1);
    __syncthreads();
    if (tid == 0) {
        int run = 0;
#pragma unroll
        for (int n = 0; n < 64; ++n) { nodeoff[n] = run; run += hist[n]; }
        nodeoff[64] = run;
    }
    __syncthreads();
    if (tid < 64) {
        int node = bkt * 64 + tid;
        if (node < NN) offs[node] = s + nodeoff[tid];
        hist[tid] = nodeoff[tid];          // reuse as relative cursor
    }
    if (bkt == B_BKT - 1 && tid == 0) offs[NN] = NE;
    __syncthreads();
    for (int i = s + tid; i < e; i += 256) {
        unsigned v = streams[i];
        int p = atomicAdd(&hist[v >> 17], 1);
        csr[s + p] = (int)(v & 0x1FFFFu);
    }
}

// one wave per node: fp32 accumulate of bf16 feat rows, scale by 1/max(deg,1).
// Proven fastest structure (61 µs): shfl-broadcast of 8 csr entries, 8
// independent full-row loads in flight, no masking/rotation on the hot path.
__global__ void k_aggregate(const unsigned short* __restrict__ featb,
                            const int* __restrict__ offs,
                            const int* __restrict__ csr,
                            unsigned short* __restrict__ aggb) {
    int lane = threadIdx.x & 63;
    int node = blockIdx.x * 4 + (threadIdx.x >> 6);
    if (node >= NN) return;
    int s0 = offs[node], s1 = offs[node + 1];
    float a0 = 0.f, a1 = 0.f;
    for (int base = s0; base < s1; base += 64) {
        int e = (base + lane < s1) ? csr[base + lane] : 0;
        int m = s1 - base; if (m > 64) m = 64;
        int j = 0;
        for (; j + 8 <= m; j += 8) {                    // 8 loads in flight
            unsigned w0 = *(const unsigned*)(featb + (size_t)__shfl(e, j + 0, 64) * NF + lane * 2);
            unsigned w1 = *(const unsigned*)(featb + (size_t)__shfl(e, j + 1, 64) * NF + lane * 2);
            unsigned w2 = *(const unsigned*)(featb + (size_t)__shfl(e, j + 2, 64) * NF + lane * 2);
            unsigned w3 = *(const unsigned*)(featb + (size_t)__shfl(e, j + 3, 64) * NF + lane * 2);
            unsigned w4 = *(const unsigned*)(featb + (size_t)__shfl(e, j + 4, 64) * NF + lane * 2);
            unsigned w5 = *(const unsigned*)(featb + (size_t)__shfl(e, j + 5, 64) * NF + lane * 2);
            unsigned w6 = *(const unsigned*)(featb + (size_t)__shfl(e, j + 6, 64) * NF + lane * 2);
            unsigned w7 = *(const unsigned*)(featb + (size_t)__shfl(e, j + 7, 64) * NF + lane * 2);
            a0 += bflo(w0) + bflo(w1) + bflo(w2) + bflo(w3)
                + bflo(w4) + bflo(w5) + bflo(w6) + bflo(w7);
            a1 += bfhi(w0) + bfhi(w1) + bfhi(w2) + bfhi(w3)
                + bfhi(w4) + bfhi(w5) + bfhi(w6) + bfhi(w7);
        }
        for (; j < m; ++j) {
            int nn = __shfl(e, j, 64);
            unsigned w = *(const unsigned*)(featb + (size_t)nn * NF + lane * 2);
            a0 += bflo(w); a1 += bfhi(w);
        }
    }
    int dg = s1 - s0; if (dg < 1) dg = 1;
    float scale = 1.0f / (float)dg;
    unsigned outw = ((unsigned)f2bf(a1 * scale) << 16) | (unsigned)f2bf(a0 * scale);
    *(unsigned*)(aggb + (size_t)node * NF + lane * 2) = outw;
}

// MFMA + epilogue for one 64-row tile (A-fragments already loaded)
static __device__ __forceinline__ void gemm_tile(
    const unsigned short* lds, const bf16x8* a, const float* bsv,
    int rb, int quad, int l15, float* __restrict__ out) {
    floatx4 acc[8];
#pragma unroll
    for (int ct = 0; ct < 8; ++ct) acc[ct] = (floatx4){0.f, 0.f, 0.f, 0.f};
#pragma unroll
    for (int ct = 0; ct < 8; ++ct) {
        int n = ct * 16 + l15;
        int rowoff = n << 8;
        int sw = n & 7;
#pragma unroll
        for (int ks = 0; ks < 8; ++ks) {
            int kg = ks * 4 + quad;
            bf16x8 b = *(const bf16x8*)(&lds[rowoff + ((kg ^ sw) << 3)]);
            acc[ct] = __builtin_amdgcn_mfma_f32_16x16x32_bf16(a[ks], b, acc[ct], 0, 0, 0);
        }
    }
#pragma unroll
    for (int r = 0; r < 4; ++r) {
        int row = rb + quad * 4 + r;
        if (row < NN) {
#pragma unroll
            for (int ct = 0; ct < 8; ++ct) {
                int col = ct * 16 + l15;
                float v = acc[ct][r] + bsv[ct];
                out[(size_t)row * NF + col] = v > 0.f ? v : 0.f;
            }
        }
    }
}

// single fused GEMM: out = relu([feat | agg_n] @ W2 + bias), K=256.
// 256-thr blocks (64KiB W-tile -> 2 blocks/CU). Each block owns two tiles
// (t, t+GEMM_G); tile-2's 8 A-loads are issued BEFORE tile-1's MFMA so each
// wave keeps 16 global loads in flight.
__global__ __launch_bounds__(256, 2) void k_gemm(
    const unsigned short* __restrict__ featb,
    const unsigned short* __restrict__ aggb,
    const unsigned short* __restrict__ w2t,
    const float* __restrict__ bias,
    float* __restrict__ out) {
    __shared__ unsigned short lds[128 * 256];   // 64 KiB
    for (int i = threadIdx.x; i < 4096; i += 256) {
        ushortx8 w = *(const ushortx8*)(w2t + i * 8);
        *(ushortx8*)(&lds[i * 8]) = w;
    }
    __syncthreads();

    int lane = threadIdx.x & 63;
    int wave = threadIdx.x >> 6;
    int quad = lane >> 4, l15 = lane & 15;

    float bsv[8];
#pragma unroll
    for (int ct = 0; ct < 8; ++ct) bsv[ct] = bias[ct * 16 + l15];

    int t0 = blockIdx.x;
    int t1 = t0 + GEMM_G;                    // may be >= NTILE (last block)
    int t1v = (t1 < NTILE) ? t1 : t0;        // safe address for the prefetch

    int rb0 = t0 * 64 + wave * 16;
    int rb1 = t1v * 64 + wave * 16;
    int ar0 = rb0 + l15; if (ar0 > NN - 1) ar0 = NN - 1;
    int ar1 = rb1 + l15; if (ar1 > NN - 1) ar1 = NN - 1;
    const unsigned short* fr0 = featb + (size_t)ar0 * NF;
    const unsigned short* ag0 = aggb + (size_t)ar0 * NF;
    const unsigned short* fr1 = featb + (size_t)ar1 * NF;
    const unsigned short* ag1 = aggb + (size_t)ar1 * NF;

    bf16x8 a0[8], a1[8];
#pragma unroll
    for (int ks = 0; ks < 4; ++ks) {         // tile-1 A-fragments
        a0[ks]     = *(const bf16x8*)(fr0 + ks * 32 + quad * 8);
        a0[4 + ks] = *(const bf16x8*)(ag0 + ks * 32 + quad * 8);
    }
#pragma unroll
    for (int ks = 0; ks < 4; ++ks) {         // tile-2 prefetch, in flight
        a1[ks]     = *(const bf16x8*)(fr1 + ks * 32 + quad * 8);
        a1[4 + ks] = *(const bf16x8*)(ag1 + ks * 32 + quad * 8);
    }

    gemm_tile(lds, a0, bsv, rb0, quad, l15, out);
    if (t1 < NTILE)
        gemm_tile(lds, a1, bsv, rb1, quad, l15, out);
}

extern "C" void kernel_launch(void* const* d_in, const int* in_sizes, int n_in,
                              void* d_out, int out_size, void* d_ws, size_t ws_size,
                              hipStream_t stream) {
    const float* feat = (const float*)d_in[0];
    const float* wu   = (const float*)d_in[1];
    const float* wv   = (const float*)d_in[2];
    const float* bias = (const float*)d_in[3];
    const int* src    = (const int*)d_in[4];
    const int* dst    = (const int*)d_in[5];
    float* out        = (float*)d_out;

    char* ws = (char*)d_ws;
    int* counts           = (int*)(ws + 0);                    //   800,256 B
    int* bsums            = (int*)(ws + 800256);               //     4,096 B
    int* offs             = (int*)(ws + 804352);               //   400,004 B
    int* csr              = (int*)(ws + 1204480);              // 6,400,000 B
    unsigned short* featb = (unsigned short*)(ws + 7604480);   // 25,600,000 B
    unsigned short* aggb  = (unsigned short*)(ws + 33204480);  // 25,600,000 B
    unsigned short* w2t   = (unsigned short*)(ws + 58804480);  //    65,536 B
    // streams aliases aggb: dead (after k_csr) before k_aggregate writes aggb
    unsigned* streams     = (unsigned*)aggb;                   // 6.4 MB

    k_setup<<<SETUP_GRID, 256, 0, stream>>>(feat, featb, wv, wu, w2t, dst, counts);
    k_scan2_a<<<SC2A, 256, 0, stream>>>(counts, bsums);
    k_scan2_b<<<1, 1024, 0, stream>>>(bsums);
    k_binscatter<<<NB2, 512, 0, stream>>>(src, dst, counts, bsums, streams);
    k_csr<<<B_BKT, 256, 0, stream>>>(streams, counts, bsums, offs, csr);
    k_aggregate<<<(NN + 3) / 4, 256, 0, stream>>>(featb, offs, csr, aggb);
    k_gemm<<<GEMM_G, 256, 0, stream>>>(featb, aggb, w2t, bias, out);
}